// Round 2
// 352.717 us; speedup vs baseline: 1.1375x; 1.1375x over previous
//
#include <hip/hip_runtime.h>
#include <hip/hip_bf16.h>

#define BB 2
#define NN 2048
#define DD 128
#define BN (BB*NN)
#define CAP 128
#define TD 16
#define QSTR 256
#define SSTR 128
#define INV_SQRT_D 0.08838834764831845f

typedef __attribute__((ext_vector_type(8))) short short8;
typedef __attribute__((ext_vector_type(4))) float f32x4;

// ---------------------------------------------------------------------------
// LDS-tiled CSR build of e_t[b,dst,src] = edge[b,src,dst]*A[b,src,dst].
// cols[] stores GLOBAL src row (b*NN + src) as ushort (BN=4096 < 65536).
// ---------------------------------------------------------------------------
__global__ __launch_bounds__(256) void build_csr(
    const float* __restrict__ A,
    const float* __restrict__ edge,
    int* __restrict__ deg, unsigned short* __restrict__ cols,
    float* __restrict__ evals)
{
    __shared__ int   cnt[TD];
    __shared__ int   csh[TD][CAP];
    __shared__ float esh[TD][CAP];

    int bid  = blockIdx.x;
    int b    = bid / (NN / TD);
    int dst0 = (bid % (NN / TD)) * TD;
    int tid  = threadIdx.x;

    if (tid < TD) cnt[tid] = 0;
    __syncthreads();

    int srcOff = tid >> 2;
    int dOff   = (tid & 3) * 4;
    const size_t base = (size_t)b * NN * NN + dst0 + dOff;

#pragma unroll 2
    for (int s0 = 0; s0 < NN; s0 += 64) {
        int src = s0 + srcOff;
        float4 a4 = *(const float4*)&A[base + (size_t)src * NN];
        float4 e4 = *(const float4*)&edge[base + (size_t)src * NN];
        int gsrc = b * NN + src;
        float av[4] = {a4.x, a4.y, a4.z, a4.w};
        float ev[4] = {e4.x, e4.y, e4.z, e4.w};
#pragma unroll
        for (int u = 0; u < 4; u++) {
            if (av[u] != 0.f) {
                int d = dOff + u;
                int slot = atomicAdd(&cnt[d], 1);
                if (slot < CAP) { csh[d][slot] = gsrc; esh[d][slot] = ev[u] * av[u]; }
            }
        }
    }
    __syncthreads();

    if (tid < TD) deg[b * NN + dst0 + tid] = min(cnt[tid], CAP);
    for (int idx = tid; idx < TD * CAP; idx += 256) {
        int d = idx / CAP, i = idx % CAP;
        if (i < min(cnt[d], CAP)) {
            size_t row = (size_t)(b * NN + dst0 + d);
            cols [row * CAP + i] = (unsigned short)csh[d][i];
            evals[row * CAP + i] = esh[d][i];
        }
    }
}

// ---------------------------------------------------------------------------
// Merged setup: weight transposes (Wt1: 512 cols, Wt2: 896 cols) + layer-0
// rank-1 projection into q(stride QSTR)/kA,vA(stride 256)/s(stride SSTR).
//   bid <  512        : Wt1 prep (HD=128)
//   512 <= bid < 1408 : Wt2 prep (HD=256)
//   1408 <= bid       : proj_l0 (1024 sub-blocks: 256 row-tiles x 4 col-grp)
// ---------------------------------------------------------------------------
__global__ __launch_bounds__(128) void setup_small(
    const float* __restrict__ node,
    const float* __restrict__ Wq0, const float* __restrict__ Wk0,
    const float* __restrict__ Wv0, const float* __restrict__ Ws0,
    const float* __restrict__ Wq1, const float* __restrict__ Wk1,
    const float* __restrict__ Wv1, const float* __restrict__ Ws1,
    const float* __restrict__ Wq2, const float* __restrict__ Wk2,
    const float* __restrict__ Wv2, const float* __restrict__ Ws2,
    __hip_bfloat16* __restrict__ Wt1, __hip_bfloat16* __restrict__ Wt2,
    float* __restrict__ q, float* __restrict__ kA,
    float* __restrict__ vA, float* __restrict__ s)
{
    __shared__ float xs[16];
    int bid = blockIdx.x;
    int t   = threadIdx.x;

    if (bid < 1408) {
        const float *Wq, *Wk, *Wv, *Ws; __hip_bfloat16* Wt; int n, HD;
        if (bid < 512) { Wq = Wq1; Wk = Wk1; Wv = Wv1; Ws = Ws1; Wt = Wt1; n = bid;       HD = DD;     }
        else           { Wq = Wq2; Wk = Wk2; Wv = Wv2; Ws = Ws2; Wt = Wt2; n = bid - 512; HD = 2 * DD; }
        const float* src; int ld; int col;
        if      (n < HD)     { src = Wq; col = n;          ld = HD; }
        else if (n < 2*HD)   { src = Wk; col = n - HD;     ld = HD; }
        else if (n < 3*HD)   { src = Wv; col = n - 2*HD;   ld = HD; }
        else                 { src = Ws; col = n - 3*HD;   ld = DD; }
        Wt[(size_t)n * DD + t] = __float2bfloat16(src[(size_t)t * ld + col]);
    } else {
        int pb   = bid - 1408;
        int row0 = (pb & (BN / 16 - 1)) * 16;
        int gy   = pb / (BN / 16);
        if (t < 16) xs[t] = node[row0 + t];
        __syncthreads();
        int col = gy * 128 + t;
        const float* W; float* out; int lcol; int ostr;
        if      (col < DD)     { W = Wq0; out = q;  ostr = QSTR; lcol = col;          }
        else if (col < 2*DD)   { W = Wk0; out = kA; ostr = 256;  lcol = col - DD;     }
        else if (col < 3*DD)   { W = Wv0; out = vA; ostr = 256;  lcol = col - 2*DD;   }
        else                   { W = Ws0; out = s;  ostr = SSTR; lcol = col - 3*DD;   }
        float wf = W[lcol];
#pragma unroll
        for (int r = 0; r < 16; r++) out[(size_t)(row0 + r) * ostr + lcol] = xs[r] * wf;
    }
}

// ---------------------------------------------------------------------------
// Fused sparse attention + next-layer projection.
// Block = 1024 threads = 16 waves = 16 dst rows (grid BN/16 = 256 = 1/CU,
// 4 waves/SIMD). Attn body identical to the verified kernel. Epilogue stages
// the 16x128 output tile in LDS as bf16, one barrier, then projects with
// 16x16x32 bf16 MFMA into next-layer buffers.
//   q and skip are updated IN PLACE (only ever read at own row, and all
//   reads complete before the barrier). k/v ping-pong (gathered across rows).
//   NCOLS == 0 -> final layer, write fp32 to out.
//   HDN = next layer's H*D; KVSI/KVSO = k/v row strides (in/out).
// ---------------------------------------------------------------------------
template<int H, bool MEANH, bool LNRELU, int NCOLS, int HDN, int KVSI, int KVSO>
__global__ __launch_bounds__(1024) void fused_attn(
    float* qio,                                   // in/out, stride QSTR
    const float* __restrict__ k,                  // stride KVSI
    const float* __restrict__ v,                  // stride KVSI
    float* sio,                                   // in/out, stride SSTR
    const int* __restrict__ deg,
    const unsigned short* __restrict__ cols,
    const float* __restrict__ evals, const float* __restrict__ We,
    const __hip_bfloat16* __restrict__ Wt,
    float* __restrict__ kn, float* __restrict__ vn,   // stride KVSO
    float* __restrict__ out)
{
    const int HD = H * DD;
    int wid  = threadIdx.x >> 6;       // 0..15
    int lane = threadIdx.x & 63;
    int row0 = blockIdx.x * 16;
    int row  = row0 + wid;
    int sub  = lane >> 4;
    int s    = lane & 15;
    int c0   = lane * 2;

    __shared__ int            jc_s[16][CAP];
    __shared__ float          ev_s[16][CAP];
    __shared__ __hip_bfloat16 xs[16][136];   // +8 bf16 pad (16B-aligned rows)
    int*   jc = jc_s[wid];
    float* ev = ev_s[wid];

    int dg = min(deg[row], CAP);
    for (int m = lane; m < dg; m += 64) {
        jc[m] = (int)cols[(size_t)row * CAP + m];
        ev[m] = evals[(size_t)row * CAP + m];
    }
    // wave-private LDS: no barrier needed (compiler inserts lgkmcnt waits)

    float qh[H][8];
    float qeI[H];
#pragma unroll
    for (int h = 0; h < H; h++) {
        const float* qp = &qio[(size_t)row * QSTR + h * DD + s * 8];
        const float* wp = &We[h * DD + s * 8];
        float pe = 0.f;
#pragma unroll
        for (int t = 0; t < 8; t++) { qh[h][t] = qp[t]; pe += qp[t] * wp[t]; }
#pragma unroll
        for (int off = 1; off < 16; off <<= 1) pe += __shfl_xor(pe, off);
        qeI[h] = pe * INV_SQRT_D;
    }

    float l_acc[H], ew_acc[H], acc[H][2];
#pragma unroll
    for (int h = 0; h < H; h++) { l_acc[h] = 0.f; ew_acc[h] = 0.f; acc[h][0] = 0.f; acc[h][1] = 0.f; }

    for (int m0 = 0; m0 < dg; m0 += 4) {
        int   e  = m0 + sub;
        bool  ok = e < dg;
        int   ec = ok ? e : m0;
        int   j  = jc[ec];
        float ee = ev[ec];

        int jb[4];
#pragma unroll
        for (int es = 0; es < 4; es++) jb[es] = jc[(m0 + es < dg) ? m0 + es : m0];
        float2 vv[H][4];
#pragma unroll
        for (int h = 0; h < H; h++)
#pragma unroll
            for (int es = 0; es < 4; es++)
                vv[h][es] = *(const float2*)&v[(size_t)jb[es] * KVSI + h * DD + c0];

#pragma unroll
        for (int h = 0; h < H; h++) {
            const float* kr = &k[(size_t)j * KVSI + h * DD + s * 8];
            float4 k0 = *(const float4*)kr;
            float4 k1 = *(const float4*)(kr + 4);
            float p = qh[h][0]*k0.x + qh[h][1]*k0.y + qh[h][2]*k0.z + qh[h][3]*k0.w
                    + qh[h][4]*k1.x + qh[h][5]*k1.y + qh[h][6]*k1.z + qh[h][7]*k1.w;
#pragma unroll
            for (int off = 1; off < 16; off <<= 1) p += __shfl_xor(p, off);
            float sc = ok ? (p * INV_SQRT_D + qeI[h] * ee) : -1e30f;
            float a4 = __expf(fminf(sc, 60.f));       // invalid -> exp(-1e30)=0
            l_acc[h]  += a4;                          // subgroup-local (x16 replicated)
            ew_acc[h] += a4 * ee;
            float al[4];
#pragma unroll
            for (int es = 0; es < 4; es++) al[es] = __shfl(a4, es * 16);
#pragma unroll
            for (int es = 0; es < 4; es++) {
                acc[h][0] += al[es] * vv[h][es].x;
                acc[h][1] += al[es] * vv[h][es].y;
            }
        }
    }

    // reduce l/ew across the 4 subgroups (values replicated within subgroup)
    float rh[H][2];
#pragma unroll
    for (int h = 0; h < H; h++) {
        float l  = l_acc[h]  + __shfl_xor(l_acc[h], 16);
        float ew = ew_acc[h] + __shfl_xor(ew_acc[h], 16);
        l  += __shfl_xor(l, 32);
        ew += __shfl_xor(ew, 32);
        float invZ = (l > 0.f) ? 1.f / l : 0.f;
        rh[h][0] = (acc[h][0] + ew * We[h * DD + c0])     * invZ;
        rh[h][1] = (acc[h][1] + ew * We[h * DD + c0 + 1]) * invZ;
    }
    float r0, r1;
    if constexpr (MEANH) {
        r0 = 0.5f * (rh[0][0] + rh[H - 1][0]);
        r1 = 0.5f * (rh[0][1] + rh[H - 1][1]);
    } else {
        r0 = rh[0][0]; r1 = rh[0][1];
    }
    float2 sk = *(const float2*)&sio[(size_t)row * SSTR + c0];
    r0 += sk.x; r1 += sk.y;

    if constexpr (LNRELU) {
        float sum = r0 + r1, sq = r0 * r0 + r1 * r1;
#pragma unroll
        for (int off = 32; off; off >>= 1) { sum += __shfl_xor(sum, off); sq += __shfl_xor(sq, off); }
        float mu  = sum * (1.f / DD);
        float var = sq * (1.f / DD) - mu * mu;
        float rs  = rsqrtf(var + 1e-5f);
        r0 = fmaxf((r0 - mu) * rs, 0.f);
        r1 = fmaxf((r1 - mu) * rs, 0.f);
    }

    if constexpr (NCOLS == 0) {
        float2 res; res.x = r0; res.y = r1;
        *(float2*)&out[(size_t)row * DD + c0] = res;
    } else {
        // stage bf16 x-tile in LDS, then MFMA-project into next-layer buffers
        __hip_bfloat162 o;
        o.x = __float2bfloat16(r0);
        o.y = __float2bfloat16(r1);
        *(__hip_bfloat162*)&xs[wid][c0] = o;
        __syncthreads();   // all attn reads (q/skip/k/v) drained before writes

        int m16 = lane & 15, quad = lane >> 4;
        short8 a[4];
#pragma unroll
        for (int ks = 0; ks < 4; ks++)
            a[ks] = *(const short8*)&xs[m16][ks * 32 + quad * 8];

#pragma unroll 1
        for (int tile = wid; tile < NCOLS / 16; tile += 16) {
            int n0 = tile * 16;
            float* o_; int lc; int od;
            if      (n0 < HDN)     { o_ = qio; lc = n0;           od = QSTR; }
            else if (n0 < 2*HDN)   { o_ = kn;  lc = n0 - HDN;     od = KVSO; }
            else if (n0 < 3*HDN)   { o_ = vn;  lc = n0 - 2*HDN;   od = KVSO; }
            else                   { o_ = sio; lc = n0 - 3*HDN;   od = SSTR; }
            f32x4 pacc = {0.f, 0.f, 0.f, 0.f};
#pragma unroll
            for (int ks = 0; ks < 4; ks++) {
                const short8* bp = (const short8*)&Wt[(size_t)(n0 + m16) * DD + ks * 32 + quad * 8];
                pacc = __builtin_amdgcn_mfma_f32_16x16x32_bf16(a[ks], *bp, pacc, 0, 0, 0);
            }
#pragma unroll
            for (int r = 0; r < 4; r++)
                o_[(size_t)(row0 + quad * 4 + r) * od + lc + m16] = pacc[r];
        }
    }
}

// ---------------------------------------------------------------------------
extern "C" void kernel_launch(void* const* d_in, const int* in_sizes, int n_in,
                              void* d_out, int out_size, void* d_ws, size_t ws_size,
                              hipStream_t stream)
{
    const float* node = (const float*)d_in[0];
    const float* edge = (const float*)d_in[1];
    const float* A    = (const float*)d_in[2];
    const float* Wq[3] = {(const float*)d_in[3],  (const float*)d_in[8],  (const float*)d_in[13]};
    const float* Wk[3] = {(const float*)d_in[4],  (const float*)d_in[9],  (const float*)d_in[14]};
    const float* Wv[3] = {(const float*)d_in[5],  (const float*)d_in[10], (const float*)d_in[15]};
    const float* We[3] = {(const float*)d_in[6],  (const float*)d_in[11], (const float*)d_in[16]};
    const float* Ws[3] = {(const float*)d_in[7],  (const float*)d_in[12], (const float*)d_in[17]};

    // workspace carve (~21.4 MiB):
    //   q (in-place, stride 256)      4 MiB
    //   s (in-place, stride 128)      2 MiB
    //   kA/vA (l0 & l2, stride 256)   8 MiB
    //   kB/vB (l1, stride 128)        4 MiB
    //   Wt1/Wt2                       0.35 MiB
    //   deg/cols(u16)/evals           3.02 MiB
    char* p = (char*)d_ws;
    float* q  = (float*)p; p += (size_t)BN * QSTR * 4;
    float* s  = (float*)p; p += (size_t)BN * SSTR * 4;
    float* kA = (float*)p; p += (size_t)BN * 256 * 4;
    float* vA = (float*)p; p += (size_t)BN * 256 * 4;
    float* kB = (float*)p; p += (size_t)BN * 128 * 4;
    float* vB = (float*)p; p += (size_t)BN * 128 * 4;
    __hip_bfloat16* Wt1 = (__hip_bfloat16*)p; p += (size_t)512 * DD * 2;
    __hip_bfloat16* Wt2 = (__hip_bfloat16*)p; p += (size_t)896 * DD * 2;
    int*            degb = (int*)p;            p += (size_t)BN * 4;
    float*          evb  = (float*)p;          p += (size_t)BN * CAP * 4;
    unsigned short* colb = (unsigned short*)p; p += (size_t)BN * CAP * 2;

    build_csr<<<BB * (NN / TD), 256, 0, stream>>>(A, edge, degb, colb, evb);
    setup_small<<<2432, 128, 0, stream>>>(node,
        Wq[0], Wk[0], Wv[0], Ws[0],
        Wq[1], Wk[1], Wv[1], Ws[1],
        Wq[2], Wk[2], Wv[2], Ws[2],
        Wt1, Wt2, q, kA, vA, s);

    // app sequence l = {0,1,2,1,2,1,2}; each kernel = attn(l) + proj(next l)
    fused_attn<1, false, true, 512, 128, 256, 128><<<BN / 16, 1024, 0, stream>>>(   // l0 -> proj l1
        q, kA, vA, s, degb, colb, evb, We[0], Wt1, kB, vB, nullptr);
    fused_attn<1, false, true, 896, 256, 128, 256><<<BN / 16, 1024, 0, stream>>>(   // l1 -> proj l2
        q, kB, vB, s, degb, colb, evb, We[1], Wt2, kA, vA, nullptr);
    fused_attn<2, true, false, 512, 128, 256, 128><<<BN / 16, 1024, 0, stream>>>(   // l2 -> proj l1
        q, kA, vA, s, degb, colb, evb, We[2], Wt1, kB, vB, nullptr);
    fused_attn<1, false, true, 896, 256, 128, 256><<<BN / 16, 1024, 0, stream>>>(   // l1 -> proj l2
        q, kB, vB, s, degb, colb, evb, We[1], Wt2, kA, vA, nullptr);
    fused_attn<2, true, false, 512, 128, 256, 128><<<BN / 16, 1024, 0, stream>>>(   // l2 -> proj l1
        q, kA, vA, s, degb, colb, evb, We[2], Wt1, kB, vB, nullptr);
    fused_attn<1, false, true, 896, 256, 128, 256><<<BN / 16, 1024, 0, stream>>>(   // l1 -> proj l2
        q, kB, vB, s, degb, colb, evb, We[1], Wt2, kA, vA, nullptr);
    fused_attn<2, true, false, 0, 0, 256, 0><<<BN / 16, 1024, 0, stream>>>(         // l2 -> output
        q, kA, vA, s, degb, colb, evb, We[2], nullptr, nullptr, nullptr, (float*)d_out);
}